// Round 1
// baseline (598.457 us; speedup 1.0000x reference)
//
#include <hip/hip_runtime.h>
#include <hip/hip_bf16.h>

#define BM 128
#define BN 128
#define BK 32

typedef float  f32x4  __attribute__((ext_vector_type(4)));
typedef int    i32x4  __attribute__((ext_vector_type(4)));
typedef __bf16 bf16x8 __attribute__((ext_vector_type(8)));
typedef __bf16 bf16x4 __attribute__((ext_vector_type(4)));

// XOR swizzle of 16B slots within a 64B (32-elem bf16) LDS row:
// slot ^= (row>>1)&3. Applied identically on write and read -> consistent.
// Breaks the 8-way bank conflict of stride-64B ds_read_b128 frag reads.
__device__ __forceinline__ int swz_elem(int row, int e) {
    return row * BK + (e ^ (((row >> 1) & 3) << 3));
}

__global__ __launch_bounds__(256, 2)
void qlin_gemm_bf16(const float* __restrict__ A,   // [M,K] f32 activations
                    const int*   __restrict__ W,   // [N,K] int32 holding int8
                    const float* __restrict__ scale, // [N]
                    const float* __restrict__ bias,  // [N]
                    float*       __restrict__ C,   // [M,N] f32
                    int M, int N, int K) {
    __shared__ __bf16 lA[2][BM * BK];
    __shared__ __bf16 lB[2][BN * BK];

    const int NTN = N / BN;
    const int nwg = gridDim.x;
    int bid = blockIdx.x;
    // XCD-aware swizzle (bijective since nwg % 8 == 0); tn-fastest ordering
    // below means each XCD sweeps contiguous tiles sharing A-panels.
    if ((nwg & 7) == 0) bid = (bid & 7) * (nwg >> 3) + (bid >> 3);
    const int tm = bid / NTN;
    const int tn = bid % NTN;

    const int tid  = threadIdx.x;
    const int lane = tid & 63;
    const int wid  = tid >> 6;
    const int wr   = wid >> 1;   // wave quadrant row (0..1)
    const int wc   = wid & 1;    // wave quadrant col (0..1)

    // Staging map: per round j (0..3), thread covers float4 slot
    // row = (tid>>3) + 32*j, kq = tid&7  -> wave reads 8 full 128B rows (coalesced)
    const int srow0 = tid >> 3;
    const int skq   = tid & 7;
    const float* aptr = A + (size_t)(tm * BM + srow0) * K + skq * 4;
    const int*   wptr = W + (size_t)(tn * BN + srow0) * K + skq * 4;
    const size_t rstride = (size_t)32 * K;

    f32x4 sa[4];
    i32x4 sw[4];

    auto LOAD = [&](int t) {
#pragma unroll
        for (int j = 0; j < 4; ++j) {
            sa[j] = *(const f32x4*)(aptr + (size_t)t * BK + j * rstride);
            sw[j] = *(const i32x4*)(wptr + (size_t)t * BK + j * rstride);
        }
    };
    auto STORE = [&](int buf) {
#pragma unroll
        for (int j = 0; j < 4; ++j) {
            const int idx = swz_elem(srow0 + j * 32, skq * 4);
            bf16x4 va = { (__bf16)sa[j][0], (__bf16)sa[j][1],
                          (__bf16)sa[j][2], (__bf16)sa[j][3] };
            // int8 values are EXACT in bf16; scale applied in epilogue.
            bf16x4 vw = { (__bf16)(float)sw[j][0], (__bf16)(float)sw[j][1],
                          (__bf16)(float)sw[j][2], (__bf16)(float)sw[j][3] };
            *(bf16x4*)&lA[buf][idx] = va;
            *(bf16x4*)&lB[buf][idx] = vw;
        }
    };

    const f32x4 fzero = {0.f, 0.f, 0.f, 0.f};
    f32x4 acc[4][4];
#pragma unroll
    for (int i = 0; i < 4; ++i)
#pragma unroll
        for (int j = 0; j < 4; ++j)
            acc[i][j] = fzero;

    const int fr  = lane & 15;        // row within 16x16 fragment
    const int fks = (lane >> 4) * 8;  // k-slot start (element units)

    LOAD(0);
    STORE(0);
    __syncthreads();

    const int NT = K / BK;
    for (int t = 0; t < NT; ++t) {
        const int buf = t & 1;
        if (t + 1 < NT) LOAD(t + 1);   // issue next tile's global loads early

        bf16x8 af[4], bfg[4];
#pragma unroll
        for (int mi = 0; mi < 4; ++mi)
            af[mi] = *(const bf16x8*)&lA[buf][swz_elem(wr * 64 + mi * 16 + fr, fks)];
#pragma unroll
        for (int ni = 0; ni < 4; ++ni)
            bfg[ni] = *(const bf16x8*)&lB[buf][swz_elem(wc * 64 + ni * 16 + fr, fks)];

#pragma unroll
        for (int mi = 0; mi < 4; ++mi)
#pragma unroll
            for (int ni = 0; ni < 4; ++ni)
                acc[mi][ni] = __builtin_amdgcn_mfma_f32_16x16x32_bf16(
                    af[mi], bfg[ni], acc[mi][ni], 0, 0, 0);

        if (t + 1 < NT) STORE(buf ^ 1);  // write next tile into other buffer
        __syncthreads();                 // one barrier per K-step
    }

    // Epilogue: C/D layout col = lane&15, row = (lane>>4)*4 + r
    const int row0 = tm * BM + wr * 64 + (lane >> 4) * 4;
    const int col0 = tn * BN + wc * 64 + fr;
#pragma unroll
    for (int ni = 0; ni < 4; ++ni) {
        const int n = col0 + ni * 16;
        const float sc = scale[n];
        const float bs = bias[n];
#pragma unroll
        for (int mi = 0; mi < 4; ++mi) {
            const int m = row0 + mi * 16;
#pragma unroll
            for (int r = 0; r < 4; ++r)
                C[(size_t)(m + r) * N + n] = fmaf(acc[mi][ni][r], sc, bs);
        }
    }
}

extern "C" void kernel_launch(void* const* d_in, const int* in_sizes, int n_in,
                              void* d_out, int out_size, void* d_ws, size_t ws_size,
                              hipStream_t stream) {
    const float* x     = (const float*)d_in[0];
    const int*   w8    = (const int*)d_in[1];
    const float* scale = (const float*)d_in[2];
    const float* bias  = (const float*)d_in[3];
    float*       out   = (float*)d_out;

    const int DOUT = in_sizes[2];            // 4096 (scale length)
    const int DIN  = in_sizes[1] / DOUT;     // 4096
    const int M    = in_sizes[0] / DIN;      // 8192 = B*S

    dim3 grid((M / BM) * (DOUT / BN));
    qlin_gemm_bf16<<<grid, 256, 0, stream>>>(x, w8, scale, bias, out, M, DOUT, DIN);
}

// Round 2
// 378.677 us; speedup vs baseline: 1.5804x; 1.5804x over previous
//
#include <hip/hip_runtime.h>
#include <hip/hip_bf16.h>

#define BM 128
#define BN 128
#define BK 32

typedef float  f32x4  __attribute__((ext_vector_type(4)));
typedef int    i32x4  __attribute__((ext_vector_type(4)));
typedef __bf16 bf16x8 __attribute__((ext_vector_type(8)));
typedef __bf16 bf16x4 __attribute__((ext_vector_type(4)));

__device__ __forceinline__ void gload_lds16(const __bf16* g, __bf16* l) {
    __builtin_amdgcn_global_load_lds(
        (const __attribute__((address_space(1))) void*)g,
        (__attribute__((address_space(3))) void*)l, 16, 0, 0);
}

// ---------------- prepass: convert inputs to bf16 in d_ws ----------------

__global__ __launch_bounds__(256)
void cvt_f32_bf16(const float* __restrict__ in, __bf16* __restrict__ out, int n8) {
    int i = blockIdx.x * blockDim.x + threadIdx.x;
    const int stride = gridDim.x * blockDim.x;
    for (; i < n8; i += stride) {
        f32x4 a = ((const f32x4*)in)[2 * i];
        f32x4 b = ((const f32x4*)in)[2 * i + 1];
        bf16x8 o = { (__bf16)a[0], (__bf16)a[1], (__bf16)a[2], (__bf16)a[3],
                     (__bf16)b[0], (__bf16)b[1], (__bf16)b[2], (__bf16)b[3] };
        ((bf16x8*)out)[i] = o;
    }
}

__global__ __launch_bounds__(256)
void cvt_i32_bf16(const int* __restrict__ in, __bf16* __restrict__ out, int n8) {
    int i = blockIdx.x * blockDim.x + threadIdx.x;
    const int stride = gridDim.x * blockDim.x;
    for (; i < n8; i += stride) {
        i32x4 a = ((const i32x4*)in)[2 * i];
        i32x4 b = ((const i32x4*)in)[2 * i + 1];
        // int8 values are exact in bf16
        bf16x8 o = { (__bf16)(float)a[0], (__bf16)(float)a[1],
                     (__bf16)(float)a[2], (__bf16)(float)a[3],
                     (__bf16)(float)b[0], (__bf16)(float)b[1],
                     (__bf16)(float)b[2], (__bf16)(float)b[3] };
        ((bf16x8*)out)[i] = o;
    }
}

// ---------------- main GEMM: m97 structure + swizzled LDS ----------------
// LDS[R][q] (q = 16B quad, 0..3) holds global quad (q ^ ((R>>1)&3)).
// gload_lds writes linearly (dest = wave base + lane*16), so the SOURCE
// address carries the inverse swizzle; ds_read applies the same XOR.

__global__ __launch_bounds__(256, 2)
void qlin_gemm_glds(const __bf16* __restrict__ A,  // [M,K] bf16 x
                    const __bf16* __restrict__ B,  // [N,K] bf16 w
                    const float* __restrict__ scale,
                    const float* __restrict__ bias,
                    float* __restrict__ C, int M, int N, int K) {
    __shared__ __bf16 lA[2][BM * BK];
    __shared__ __bf16 lB[2][BN * BK];

    const int NTN = N / BN;
    const int nwg = gridDim.x;
    int bid = blockIdx.x;
    bid = (bid & 7) * (nwg >> 3) + (bid >> 3);   // XCD swizzle (nwg%8==0)
    const int tm = bid / NTN;
    const int tn = bid % NTN;

    const int tid  = threadIdx.x;
    const int lane = tid & 63;
    const int wid  = tid >> 6;
    const int wr   = wid >> 1;
    const int wc   = wid & 1;

    // staging map: thread covers LDS row srow (0..63) + issue*64, quad scq
    const int srow = tid >> 2;
    const int scq  = tid & 3;

    const int NT = K / BK;

    auto STAGE = [&](int t, int buf) {
#pragma unroll
        for (int i = 0; i < 2; ++i) {
            const int rA = i * 64 + srow;
            const int gq = scq ^ ((rA >> 1) & 3);
            gload_lds16(A + (size_t)(tm * BM + rA) * K + t * BK + gq * 8,
                        &lA[buf][i * 2048 + wid * 512]);
        }
#pragma unroll
        for (int i = 0; i < 2; ++i) {
            const int rB = i * 64 + srow;
            const int gq = scq ^ ((rB >> 1) & 3);
            gload_lds16(B + (size_t)(tn * BN + rB) * K + t * BK + gq * 8,
                        &lB[buf][i * 2048 + wid * 512]);
        }
    };

    const f32x4 fzero = {0.f, 0.f, 0.f, 0.f};
    f32x4 acc[4][4];
#pragma unroll
    for (int i = 0; i < 4; ++i)
#pragma unroll
        for (int j = 0; j < 4; ++j) acc[i][j] = fzero;

    const int fr = lane & 15;
    const int fs = lane >> 4;  // k-quad 0..3

    STAGE(0, 0);
    __syncthreads();

    for (int t = 0; t < NT; ++t) {
        const int buf = t & 1;
        if (t + 1 < NT) STAGE(t + 1, buf ^ 1);

        bf16x8 af[4], bfg[4];
#pragma unroll
        for (int mi = 0; mi < 4; ++mi) {
            const int R = wr * 64 + mi * 16 + fr;
            af[mi] = *(const bf16x8*)&lA[buf][R * BK + ((fs ^ ((R >> 1) & 3)) << 3)];
        }
#pragma unroll
        for (int ni = 0; ni < 4; ++ni) {
            const int R = wc * 64 + ni * 16 + fr;
            bfg[ni] = *(const bf16x8*)&lB[buf][R * BK + ((fs ^ ((R >> 1) & 3)) << 3)];
        }

#pragma unroll
        for (int mi = 0; mi < 4; ++mi)
#pragma unroll
            for (int ni = 0; ni < 4; ++ni)
                acc[mi][ni] = __builtin_amdgcn_mfma_f32_16x16x32_bf16(
                    af[mi], bfg[ni], acc[mi][ni], 0, 0, 0);

        __syncthreads();  // drains vmcnt -> buf^1 staged; WAR-safe for next STAGE
    }

    const int row0 = tm * BM + wr * 64 + (lane >> 4) * 4;
    const int col0 = tn * BN + wc * 64 + fr;
#pragma unroll
    for (int ni = 0; ni < 4; ++ni) {
        const int n = col0 + ni * 16;
        const float sc = scale[n];
        const float bs = bias[n];
#pragma unroll
        for (int mi = 0; mi < 4; ++mi) {
            const int m = row0 + mi * 16;
#pragma unroll
            for (int r = 0; r < 4; ++r)
                C[(size_t)(m + r) * N + n] = fmaf(acc[mi][ni][r], sc, bs);
        }
    }
}

// ---------------- fallback (round-1 kernel) if ws too small ----------------

__device__ __forceinline__ int swz_elem(int row, int e) {
    return row * BK + (e ^ (((row >> 1) & 3) << 3));
}

__global__ __launch_bounds__(256, 2)
void qlin_gemm_reg(const float* __restrict__ A, const int* __restrict__ W,
                   const float* __restrict__ scale, const float* __restrict__ bias,
                   float* __restrict__ C, int M, int N, int K) {
    __shared__ __bf16 lA[2][BM * BK];
    __shared__ __bf16 lB[2][BN * BK];
    const int NTN = N / BN;
    const int nwg = gridDim.x;
    int bid = blockIdx.x;
    if ((nwg & 7) == 0) bid = (bid & 7) * (nwg >> 3) + (bid >> 3);
    const int tm = bid / NTN, tn = bid % NTN;
    const int tid = threadIdx.x, lane = tid & 63, wid = tid >> 6;
    const int wr = wid >> 1, wc = wid & 1;
    const int srow0 = tid >> 3, skq = tid & 7;
    const float* aptr = A + (size_t)(tm * BM + srow0) * K + skq * 4;
    const int*   wptr = W + (size_t)(tn * BN + srow0) * K + skq * 4;
    const size_t rstride = (size_t)32 * K;
    f32x4 sa[4]; i32x4 sw[4];
    auto LOAD = [&](int t) {
#pragma unroll
        for (int j = 0; j < 4; ++j) {
            sa[j] = *(const f32x4*)(aptr + (size_t)t * BK + j * rstride);
            sw[j] = *(const i32x4*)(wptr + (size_t)t * BK + j * rstride);
        }
    };
    auto STORE = [&](int buf) {
#pragma unroll
        for (int j = 0; j < 4; ++j) {
            const int idx = swz_elem(srow0 + j * 32, skq * 4);
            bf16x4 va = { (__bf16)sa[j][0], (__bf16)sa[j][1],
                          (__bf16)sa[j][2], (__bf16)sa[j][3] };
            bf16x4 vw = { (__bf16)(float)sw[j][0], (__bf16)(float)sw[j][1],
                          (__bf16)(float)sw[j][2], (__bf16)(float)sw[j][3] };
            *(bf16x4*)&lA[buf][idx] = va;
            *(bf16x4*)&lB[buf][idx] = vw;
        }
    };
    const f32x4 fzero = {0.f, 0.f, 0.f, 0.f};
    f32x4 acc[4][4];
#pragma unroll
    for (int i = 0; i < 4; ++i)
#pragma unroll
        for (int j = 0; j < 4; ++j) acc[i][j] = fzero;
    const int fr = lane & 15, fks = (lane >> 4) * 8;
    LOAD(0); STORE(0); __syncthreads();
    const int NT = K / BK;
    for (int t = 0; t < NT; ++t) {
        const int buf = t & 1;
        if (t + 1 < NT) LOAD(t + 1);
        bf16x8 af[4], bfg[4];
#pragma unroll
        for (int mi = 0; mi < 4; ++mi)
            af[mi] = *(const bf16x8*)&lA[buf][swz_elem(wr * 64 + mi * 16 + fr, fks)];
#pragma unroll
        for (int ni = 0; ni < 4; ++ni)
            bfg[ni] = *(const bf16x8*)&lB[buf][swz_elem(wc * 64 + ni * 16 + fr, fks)];
#pragma unroll
        for (int mi = 0; mi < 4; ++mi)
#pragma unroll
            for (int ni = 0; ni < 4; ++ni)
                acc[mi][ni] = __builtin_amdgcn_mfma_f32_16x16x32_bf16(
                    af[mi], bfg[ni], acc[mi][ni], 0, 0, 0);
        if (t + 1 < NT) STORE(buf ^ 1);
        __syncthreads();
    }
    const int row0 = tm * BM + wr * 64 + (lane >> 4) * 4;
    const int col0 = tn * BN + wc * 64 + fr;
#pragma unroll
    for (int ni = 0; ni < 4; ++ni) {
        const int n = col0 + ni * 16;
        const float sc = scale[n], bs = bias[n];
#pragma unroll
        for (int mi = 0; mi < 4; ++mi) {
            const int m = row0 + mi * 16;
#pragma unroll
            for (int r = 0; r < 4; ++r)
                C[(size_t)(m + r) * N + n] = fmaf(acc[mi][ni][r], sc, bs);
        }
    }
}

extern "C" void kernel_launch(void* const* d_in, const int* in_sizes, int n_in,
                              void* d_out, int out_size, void* d_ws, size_t ws_size,
                              hipStream_t stream) {
    const float* x     = (const float*)d_in[0];
    const int*   w8    = (const int*)d_in[1];
    const float* scale = (const float*)d_in[2];
    const float* bias  = (const float*)d_in[3];
    float*       out   = (float*)d_out;

    const int DOUT = in_sizes[2];
    const int DIN  = in_sizes[1] / DOUT;
    const int M    = in_sizes[0] / DIN;

    const size_t need = ((size_t)M * DIN + (size_t)DOUT * DIN) * sizeof(__bf16);
    if (ws_size >= need) {
        __bf16* xb = (__bf16*)d_ws;
        __bf16* wb = xb + (size_t)M * DIN;
        cvt_f32_bf16<<<1024, 256, 0, stream>>>(x, xb, M * DIN / 8);
        cvt_i32_bf16<<<1024, 256, 0, stream>>>(w8, wb, DOUT * DIN / 8);
        dim3 grid((M / BM) * (DOUT / BN));
        qlin_gemm_glds<<<grid, 256, 0, stream>>>(xb, wb, scale, bias, out, M, DOUT, DIN);
    } else {
        dim3 grid((M / BM) * (DOUT / BN));
        qlin_gemm_reg<<<grid, 256, 0, stream>>>(x, w8, scale, bias, out, M, DOUT, DIN);
    }
}

// Round 3
// 307.495 us; speedup vs baseline: 1.9462x; 1.2315x over previous
//
#include <hip/hip_runtime.h>
#include <hip/hip_bf16.h>

// ---------------- 256x256 counted-vmcnt GEMM (T1+T2+T3/T4+T5) ----------------
#define BM 256
#define BN 256
#define BK 32
#define NSLOT 4   // ring of 4 K-tile slots, staged 3 ahead

typedef float  f32x4  __attribute__((ext_vector_type(4)));
typedef int    i32x4  __attribute__((ext_vector_type(4)));
typedef __bf16 bf16x8 __attribute__((ext_vector_type(8)));
typedef __bf16 bf16x4 __attribute__((ext_vector_type(4)));

__device__ __forceinline__ void gload_lds16(const __bf16* g, __bf16* l) {
    __builtin_amdgcn_global_load_lds(
        (const __attribute__((address_space(1))) void*)g,
        (__attribute__((address_space(3))) void*)l, 16, 0, 0);
}

// ---------------- prepass: convert inputs to bf16 in d_ws ----------------

__global__ __launch_bounds__(256)
void cvt_f32_bf16(const float* __restrict__ in, __bf16* __restrict__ out, int n8) {
    int i = blockIdx.x * blockDim.x + threadIdx.x;
    const int stride = gridDim.x * blockDim.x;
    for (; i < n8; i += stride) {
        f32x4 a = ((const f32x4*)in)[2 * i];
        f32x4 b = ((const f32x4*)in)[2 * i + 1];
        bf16x8 o = { (__bf16)a[0], (__bf16)a[1], (__bf16)a[2], (__bf16)a[3],
                     (__bf16)b[0], (__bf16)b[1], (__bf16)b[2], (__bf16)b[3] };
        ((bf16x8*)out)[i] = o;
    }
}

__global__ __launch_bounds__(256)
void cvt_i32_bf16(const int* __restrict__ in, __bf16* __restrict__ out, int n8) {
    int i = blockIdx.x * blockDim.x + threadIdx.x;
    const int stride = gridDim.x * blockDim.x;
    for (; i < n8; i += stride) {
        i32x4 a = ((const i32x4*)in)[2 * i];
        i32x4 b = ((const i32x4*)in)[2 * i + 1];
        bf16x8 o = { (__bf16)(float)a[0], (__bf16)(float)a[1],
                     (__bf16)(float)a[2], (__bf16)(float)a[3],
                     (__bf16)(float)b[0], (__bf16)(float)b[1],
                     (__bf16)(float)b[2], (__bf16)(float)b[3] };
        ((bf16x8*)out)[i] = o;
    }
}

// ---------------- main GEMM ----------------
// LDS slot layout: [256 rows][32 bf16] per operand, 4 slots each (128 KiB).
// XOR swizzle: 16B quad q of row R holds global quad q ^ ((R>>1)&3).
// gload_lds writes linearly -> inverse swizzle on the GLOBAL source address;
// ds_read applies the same XOR (both-sides discipline, rule #21).

__global__ __launch_bounds__(512, 2)
void qlin_gemm_8ph(const __bf16* __restrict__ A,  // [M,K]
                   const __bf16* __restrict__ B,  // [N,K]
                   const float* __restrict__ scale,
                   const float* __restrict__ bias,
                   float* __restrict__ C, int M, int N, int K) {
    extern __shared__ __bf16 lds[];
    __bf16* lA = lds;                         // [NSLOT][BM*BK]
    __bf16* lB = lds + NSLOT * (BM * BK);     // [NSLOT][BN*BK]

    const int NTN = N / BN;
    const int nwg = gridDim.x;
    int bid = blockIdx.x;
    bid = (bid & 7) * (nwg >> 3) + (bid >> 3);    // XCD swizzle (nwg%8==0)
    const int tm = bid / NTN;
    const int tn = bid % NTN;

    const int tid  = threadIdx.x;
    const int lane = tid & 63;
    const int wid  = tid >> 6;     // 0..7
    const int wr   = wid >> 2;     // 0..1  (M half)
    const int wc   = wid & 3;      // 0..3  (N quarter)

    // staging map: thread covers row j*128 + (tid>>2), quad tid&3
    const int srow = tid >> 2;
    const int scq  = tid & 3;
    const __bf16* Abase = A + (size_t)(tm * BM) * K;
    const __bf16* Bbase = B + (size_t)(tn * BN) * K;

    const int NT = K / BK;

    auto STAGE_A = [&](int t) {
        const int s = t & (NSLOT - 1);
#pragma unroll
        for (int j = 0; j < 2; ++j) {
            const int R  = j * 128 + srow;
            const int gq = scq ^ ((R >> 1) & 3);
            gload_lds16(Abase + (size_t)R * K + t * BK + gq * 8,
                        lA + s * (BM * BK) + (j * 128 + wid * 16) * BK);
        }
    };
    auto STAGE_B = [&](int t) {
        const int s = t & (NSLOT - 1);
#pragma unroll
        for (int j = 0; j < 2; ++j) {
            const int R  = j * 128 + srow;
            const int gq = scq ^ ((R >> 1) & 3);
            gload_lds16(Bbase + (size_t)R * K + t * BK + gq * 8,
                        lB + s * (BM * BK) + (j * 128 + wid * 16) * BK);
        }
    };

    const int fr = lane & 15;      // row within fragment
    const int fs = lane >> 4;      // k-quad 0..3

    const f32x4 fzero = {0.f, 0.f, 0.f, 0.f};
    f32x4 acc[8][4];
#pragma unroll
    for (int i = 0; i < 8; ++i)
#pragma unroll
        for (int j = 0; j < 4; ++j) acc[i][j] = fzero;

    // prologue: stage tiles 0..2 (12 loads/thread)
    for (int u = 0; u < 3 && u < NT; ++u) { STAGE_A(u); STAGE_B(u); }

    bf16x8 bfrag[4];
    for (int t = 0; t < NT; ++t) {
        const __bf16* lAs = lA + (t & (NSLOT - 1)) * (BM * BK);
        const __bf16* lBs = lB + (t & (NSLOT - 1)) * (BM * BK);

        // counted vmcnt: tile t's 4 loads are the oldest outstanding
        const int rem = NT - 1 - t;
        if (rem >= 2)      asm volatile("s_waitcnt vmcnt(8)" ::: "memory");
        else if (rem == 1) asm volatile("s_waitcnt vmcnt(4)" ::: "memory");
        else               asm volatile("s_waitcnt vmcnt(0)" ::: "memory");
        __builtin_amdgcn_s_barrier();

        // ---- phase 0: M-half 0, read B frags (kept for phase 1) ----
        if (t + 3 < NT) STAGE_A(t + 3);
        bf16x8 af[4];
#pragma unroll
        for (int mi = 0; mi < 4; ++mi) {
            const int R = wr * 128 + mi * 16 + fr;
            af[mi] = *(const bf16x8*)(lAs + R * BK + ((fs ^ ((R >> 1) & 3)) << 3));
        }
#pragma unroll
        for (int ni = 0; ni < 4; ++ni) {
            const int R = wc * 64 + ni * 16 + fr;
            bfrag[ni] = *(const bf16x8*)(lBs + R * BK + ((fs ^ ((R >> 1) & 3)) << 3));
        }
        __builtin_amdgcn_s_setprio(1);
#pragma unroll
        for (int mi = 0; mi < 4; ++mi)
#pragma unroll
            for (int ni = 0; ni < 4; ++ni)
                acc[mi][ni] = __builtin_amdgcn_mfma_f32_16x16x32_bf16(
                    af[mi], bfrag[ni], acc[mi][ni], 0, 0, 0);
        __builtin_amdgcn_s_setprio(0);
        __builtin_amdgcn_s_barrier();   // mid-tile lockstep (no drain)

        // ---- phase 1: M-half 1, reuse B frags ----
        if (t + 3 < NT) STAGE_B(t + 3);
#pragma unroll
        for (int mi = 0; mi < 4; ++mi) {
            const int R = wr * 128 + 64 + mi * 16 + fr;
            af[mi] = *(const bf16x8*)(lAs + R * BK + ((fs ^ ((R >> 1) & 3)) << 3));
        }
        __builtin_amdgcn_s_setprio(1);
#pragma unroll
        for (int mi = 0; mi < 4; ++mi)
#pragma unroll
            for (int ni = 0; ni < 4; ++ni)
                acc[4 + mi][ni] = __builtin_amdgcn_mfma_f32_16x16x32_bf16(
                    af[mi], bfrag[ni], acc[4 + mi][ni], 0, 0, 0);
        __builtin_amdgcn_s_setprio(0);
    }

    // epilogue: C/D layout col = lane&15, row = (lane>>4)*4 + r
    const int row0 = tm * BM + wr * 128 + (lane >> 4) * 4;
    const int col0 = tn * BN + wc * 64 + fr;
#pragma unroll
    for (int ni = 0; ni < 4; ++ni) {
        const int n = col0 + ni * 16;
        const float sc = scale[n];
        const float bs = bias[n];
#pragma unroll
        for (int mi = 0; mi < 8; ++mi) {
            const int m = row0 + mi * 16;
#pragma unroll
            for (int r = 0; r < 4; ++r)
                C[(size_t)(m + r) * N + n] = fmaf(acc[mi][ni][r], sc, bs);
        }
    }
}

// ---------------- fallback (round-1 reg-staged 128^2) ----------------

#define FBM 128
#define FBK 32

__device__ __forceinline__ int swz_elem(int row, int e) {
    return row * FBK + (e ^ (((row >> 1) & 3) << 3));
}

__global__ __launch_bounds__(256, 2)
void qlin_gemm_reg(const float* __restrict__ A, const int* __restrict__ W,
                   const float* __restrict__ scale, const float* __restrict__ bias,
                   float* __restrict__ C, int M, int N, int K) {
    __shared__ __bf16 lA[2][FBM * FBK];
    __shared__ __bf16 lB[2][FBM * FBK];
    const int NTN = N / FBM;
    const int nwg = gridDim.x;
    int bid = blockIdx.x;
    if ((nwg & 7) == 0) bid = (bid & 7) * (nwg >> 3) + (bid >> 3);
    const int tm = bid / NTN, tn = bid % NTN;
    const int tid = threadIdx.x, lane = tid & 63, wid = tid >> 6;
    const int wr = wid >> 1, wc = wid & 1;
    const int srow0 = tid >> 3, skq = tid & 7;
    const float* aptr = A + (size_t)(tm * FBM + srow0) * K + skq * 4;
    const int*   wptr = W + (size_t)(tn * FBM + srow0) * K + skq * 4;
    const size_t rstride = (size_t)32 * K;
    f32x4 sa[4]; i32x4 sw[4];
    auto LOAD = [&](int t) {
#pragma unroll
        for (int j = 0; j < 4; ++j) {
            sa[j] = *(const f32x4*)(aptr + (size_t)t * FBK + j * rstride);
            sw[j] = *(const i32x4*)(wptr + (size_t)t * FBK + j * rstride);
        }
    };
    auto STORE = [&](int buf) {
#pragma unroll
        for (int j = 0; j < 4; ++j) {
            const int idx = swz_elem(srow0 + j * 32, skq * 4);
            bf16x4 va = { (__bf16)sa[j][0], (__bf16)sa[j][1],
                          (__bf16)sa[j][2], (__bf16)sa[j][3] };
            bf16x4 vw = { (__bf16)(float)sw[j][0], (__bf16)(float)sw[j][1],
                          (__bf16)(float)sw[j][2], (__bf16)(float)sw[j][3] };
            *(bf16x4*)&lA[buf][idx] = va;
            *(bf16x4*)&lB[buf][idx] = vw;
        }
    };
    const f32x4 fzero = {0.f, 0.f, 0.f, 0.f};
    f32x4 acc[4][4];
#pragma unroll
    for (int i = 0; i < 4; ++i)
#pragma unroll
        for (int j = 0; j < 4; ++j) acc[i][j] = fzero;
    const int fr = lane & 15, fks = (lane >> 4) * 8;
    LOAD(0); STORE(0); __syncthreads();
    const int NT = K / FBK;
    for (int t = 0; t < NT; ++t) {
        const int buf = t & 1;
        if (t + 1 < NT) LOAD(t + 1);
        bf16x8 af[4], bfg[4];
#pragma unroll
        for (int mi = 0; mi < 4; ++mi)
            af[mi] = *(const bf16x8*)&lA[buf][swz_elem(wr * 64 + mi * 16 + fr, fks)];
#pragma unroll
        for (int ni = 0; ni < 4; ++ni)
            bfg[ni] = *(const bf16x8*)&lB[buf][swz_elem(wc * 64 + ni * 16 + fr, fks)];
#pragma unroll
        for (int mi = 0; mi < 4; ++mi)
#pragma unroll
            for (int ni = 0; ni < 4; ++ni)
                acc[mi][ni] = __builtin_amdgcn_mfma_f32_16x16x32_bf16(
                    af[mi], bfg[ni], acc[mi][ni], 0, 0, 0);
        if (t + 1 < NT) STORE(buf ^ 1);
        __syncthreads();
    }
    const int row0 = tm * FBM + wr * 64 + (lane >> 4) * 4;
    const int col0 = tn * FBM + wc * 64 + fr;
#pragma unroll
    for (int ni = 0; ni < 4; ++ni) {
        const int n = col0 + ni * 16;
        const float sc = scale[n], bs = bias[n];
#pragma unroll
        for (int mi = 0; mi < 4; ++mi) {
            const int m = row0 + mi * 16;
#pragma unroll
            for (int r = 0; r < 4; ++r)
                C[(size_t)(m + r) * N + n] = fmaf(acc[mi][ni][r], sc, bs);
        }
    }
}

extern "C" void kernel_launch(void* const* d_in, const int* in_sizes, int n_in,
                              void* d_out, int out_size, void* d_ws, size_t ws_size,
                              hipStream_t stream) {
    const float* x     = (const float*)d_in[0];
    const int*   w8    = (const int*)d_in[1];
    const float* scale = (const float*)d_in[2];
    const float* bias  = (const float*)d_in[3];
    float*       out   = (float*)d_out;

    const int DOUT = in_sizes[2];
    const int DIN  = in_sizes[1] / DOUT;
    const int M    = in_sizes[0] / DIN;

    const size_t need = ((size_t)M * DIN + (size_t)DOUT * DIN) * sizeof(__bf16);
    const int nwg = (M / BM) * (DOUT / BN);
    const bool ok8 = (ws_size >= need) && (M % BM == 0) && (DOUT % BN == 0) &&
                     (DIN % BK == 0) && (nwg % 8 == 0) && (DIN / BK >= 4);
    if (ok8) {
        __bf16* xb = (__bf16*)d_ws;
        __bf16* wb = xb + (size_t)M * DIN;
        cvt_f32_bf16<<<1024, 256, 0, stream>>>(x, xb, M * DIN / 8);
        cvt_i32_bf16<<<1024, 256, 0, stream>>>(w8, wb, DOUT * DIN / 8);
        hipFuncSetAttribute(reinterpret_cast<const void*>(qlin_gemm_8ph),
                            hipFuncAttributeMaxDynamicSharedMemorySize, 131072);
        qlin_gemm_8ph<<<nwg, 512, 131072, stream>>>(xb, wb, scale, bias, out,
                                                    M, DOUT, DIN);
    } else {
        dim3 grid((M / FBM) * (DOUT / FBM));
        qlin_gemm_reg<<<grid, 256, 0, stream>>>(x, w8, scale, bias, out, M, DOUT, DIN);
    }
}

// Round 4
// 294.843 us; speedup vs baseline: 2.0297x; 1.0429x over previous
//
#include <hip/hip_runtime.h>
#include <hip/hip_bf16.h>

// -------- 256x256 counted-vmcnt GEMM, free-run inner loop (1 barrier/tile) ----
#define BM 256
#define BN 256
#define BK 32
#define NSLOT 4   // ring of 4 K-tile slots, staged 3 ahead

typedef float  f32x4  __attribute__((ext_vector_type(4)));
typedef int    i32x4  __attribute__((ext_vector_type(4)));
typedef __bf16 bf16x8 __attribute__((ext_vector_type(8)));
typedef __bf16 bf16x4 __attribute__((ext_vector_type(4)));

__device__ __forceinline__ void gload_lds16(const __bf16* g, __bf16* l) {
    __builtin_amdgcn_global_load_lds(
        (const __attribute__((address_space(1))) void*)g,
        (__attribute__((address_space(3))) void*)l, 16, 0, 0);
}

// ---------------- prepass: convert inputs to bf16 in d_ws ----------------

__global__ __launch_bounds__(256)
void cvt_f32_bf16(const float* __restrict__ in, __bf16* __restrict__ out, int n8) {
    int i = blockIdx.x * blockDim.x + threadIdx.x;
    const int stride = gridDim.x * blockDim.x;
    for (; i < n8; i += stride) {
        f32x4 a = ((const f32x4*)in)[2 * i];
        f32x4 b = ((const f32x4*)in)[2 * i + 1];
        bf16x8 o = { (__bf16)a[0], (__bf16)a[1], (__bf16)a[2], (__bf16)a[3],
                     (__bf16)b[0], (__bf16)b[1], (__bf16)b[2], (__bf16)b[3] };
        ((bf16x8*)out)[i] = o;
    }
}

__global__ __launch_bounds__(256)
void cvt_i32_bf16(const int* __restrict__ in, __bf16* __restrict__ out, int n8) {
    int i = blockIdx.x * blockDim.x + threadIdx.x;
    const int stride = gridDim.x * blockDim.x;
    for (; i < n8; i += stride) {
        i32x4 a = ((const i32x4*)in)[2 * i];
        i32x4 b = ((const i32x4*)in)[2 * i + 1];
        bf16x8 o = { (__bf16)(float)a[0], (__bf16)(float)a[1],
                     (__bf16)(float)a[2], (__bf16)(float)a[3],
                     (__bf16)(float)b[0], (__bf16)(float)b[1],
                     (__bf16)(float)b[2], (__bf16)(float)b[3] };
        ((bf16x8*)out)[i] = o;
    }
}

// ---------------- main GEMM ----------------
// LDS slot layout: [256 rows][32 bf16] per operand, 4 slots each (128 KiB).
// XOR swizzle: 16B quad q of row R holds global quad q ^ ((R>>1)&3).
// gload_lds writes linearly -> inverse swizzle on the GLOBAL source address;
// ds_read applies the same XOR (both-sides discipline).
//
// Sync design (free-run):
//  - ONE raw s_barrier per K-tile, preceded by counted vmcnt (8/4/0 ladder).
//  - No mid-tile barrier: slot staged at distance 3 (slot (t+3)&3) was last
//    read at tile t-1; every wave passed tile t's boundary barrier only after
//    its t-1 reads drained (lgkmcnt), so the re-stage is WAR-safe.
//  - Compiler is free to hoist phase-1 ds_reads above phase-0 MFMA (same
//    slot, independent) -> read latency hides under MFMA.

__global__ __launch_bounds__(512, 2)
void qlin_gemm_8ph(const __bf16* __restrict__ A,  // [M,K]
                   const __bf16* __restrict__ B,  // [N,K]
                   const float* __restrict__ scale,
                   const float* __restrict__ bias,
                   float* __restrict__ C, int M, int N, int K) {
    extern __shared__ __bf16 lds[];
    __bf16* lA = lds;                         // [NSLOT][BM*BK]
    __bf16* lB = lds + NSLOT * (BM * BK);     // [NSLOT][BN*BK]

    const int NTN = N / BN;
    const int nwg = gridDim.x;
    int bid = blockIdx.x;
    bid = (bid & 7) * (nwg >> 3) + (bid >> 3);    // XCD swizzle (nwg%8==0)
    const int tm = bid / NTN;
    const int tn = bid % NTN;

    const int tid  = threadIdx.x;
    const int lane = tid & 63;
    const int wid  = tid >> 6;     // 0..7
    const int wr   = wid >> 2;     // 0..1  (M half)
    const int wc   = wid & 3;      // 0..3  (N quarter)

    // staging map: thread covers row j*128 + (tid>>2), quad tid&3
    const int srow = tid >> 2;
    const int scq  = tid & 3;
    const __bf16* Abase = A + (size_t)(tm * BM) * K;
    const __bf16* Bbase = B + (size_t)(tn * BN) * K;

    const int NT = K / BK;

    auto STAGE_A = [&](int t) {
        const int s = t & (NSLOT - 1);
#pragma unroll
        for (int j = 0; j < 2; ++j) {
            const int R  = j * 128 + srow;
            const int gq = scq ^ ((R >> 1) & 3);
            gload_lds16(Abase + (size_t)R * K + t * BK + gq * 8,
                        lA + s * (BM * BK) + (j * 128 + wid * 16) * BK);
        }
    };
    auto STAGE_B = [&](int t) {
        const int s = t & (NSLOT - 1);
#pragma unroll
        for (int j = 0; j < 2; ++j) {
            const int R  = j * 128 + srow;
            const int gq = scq ^ ((R >> 1) & 3);
            gload_lds16(Bbase + (size_t)R * K + t * BK + gq * 8,
                        lB + s * (BM * BK) + (j * 128 + wid * 16) * BK);
        }
    };

    const int fr = lane & 15;      // row within fragment
    const int fs = lane >> 4;      // k-quad 0..3

    const f32x4 fzero = {0.f, 0.f, 0.f, 0.f};
    f32x4 acc[8][4];
#pragma unroll
    for (int i = 0; i < 8; ++i)
#pragma unroll
        for (int j = 0; j < 4; ++j) acc[i][j] = fzero;

    // prologue: stage tiles 0..2 (12 loads/thread)
    for (int u = 0; u < 3 && u < NT; ++u) { STAGE_A(u); STAGE_B(u); }

    bf16x8 bfrag[4];
    for (int t = 0; t < NT; ++t) {
        const __bf16* lAs = lA + (t & (NSLOT - 1)) * (BM * BK);
        const __bf16* lBs = lB + (t & (NSLOT - 1)) * (BM * BK);

        // counted vmcnt: tile t's 4 loads are the oldest outstanding
        const int rem = NT - 1 - t;
        if (rem >= 2)      asm volatile("s_waitcnt vmcnt(8)" ::: "memory");
        else if (rem == 1) asm volatile("s_waitcnt vmcnt(4)" ::: "memory");
        else               asm volatile("s_waitcnt vmcnt(0)" ::: "memory");
        __builtin_amdgcn_s_barrier();   // ONLY barrier this K-tile

        // ---- phase 0: M-half 0; B frags kept for phase 1 ----
        if (t + 3 < NT) STAGE_A(t + 3);
        bf16x8 af[4];
#pragma unroll
        for (int mi = 0; mi < 4; ++mi) {
            const int R = wr * 128 + mi * 16 + fr;
            af[mi] = *(const bf16x8*)(lAs + R * BK + ((fs ^ ((R >> 1) & 3)) << 3));
        }
#pragma unroll
        for (int ni = 0; ni < 4; ++ni) {
            const int R = wc * 64 + ni * 16 + fr;
            bfrag[ni] = *(const bf16x8*)(lBs + R * BK + ((fs ^ ((R >> 1) & 3)) << 3));
        }
        __builtin_amdgcn_s_setprio(1);
#pragma unroll
        for (int mi = 0; mi < 4; ++mi)
#pragma unroll
            for (int ni = 0; ni < 4; ++ni)
                acc[mi][ni] = __builtin_amdgcn_mfma_f32_16x16x32_bf16(
                    af[mi], bfrag[ni], acc[mi][ni], 0, 0, 0);
        __builtin_amdgcn_s_setprio(0);

        // ---- phase 1: M-half 1, reuse B frags (no barrier between phases) ----
        if (t + 3 < NT) STAGE_B(t + 3);
#pragma unroll
        for (int mi = 0; mi < 4; ++mi) {
            const int R = wr * 128 + 64 + mi * 16 + fr;
            af[mi] = *(const bf16x8*)(lAs + R * BK + ((fs ^ ((R >> 1) & 3)) << 3));
        }
        __builtin_amdgcn_s_setprio(1);
#pragma unroll
        for (int mi = 0; mi < 4; ++mi)
#pragma unroll
            for (int ni = 0; ni < 4; ++ni)
                acc[4 + mi][ni] = __builtin_amdgcn_mfma_f32_16x16x32_bf16(
                    af[mi], bfrag[ni], acc[4 + mi][ni], 0, 0, 0);
        __builtin_amdgcn_s_setprio(0);
    }

    // epilogue: C/D layout col = lane&15, row = (lane>>4)*4 + r
    const int row0 = tm * BM + wr * 128 + (lane >> 4) * 4;
    const int col0 = tn * BN + wc * 64 + fr;
#pragma unroll
    for (int ni = 0; ni < 4; ++ni) {
        const int n = col0 + ni * 16;
        const float sc = scale[n];
        const float bs = bias[n];
#pragma unroll
        for (int mi = 0; mi < 8; ++mi) {
            const int m = row0 + mi * 16;
#pragma unroll
            for (int r = 0; r < 4; ++r)
                C[(size_t)(m + r) * N + n] = fmaf(acc[mi][ni][r], sc, bs);
        }
    }
}

// ---------------- fallback (reg-staged 128^2) ----------------

#define FBM 128
#define FBK 32

__device__ __forceinline__ int swz_elem(int row, int e) {
    return row * FBK + (e ^ (((row >> 1) & 3) << 3));
}

__global__ __launch_bounds__(256, 2)
void qlin_gemm_reg(const float* __restrict__ A, const int* __restrict__ W,
                   const float* __restrict__ scale, const float* __restrict__ bias,
                   float* __restrict__ C, int M, int N, int K) {
    __shared__ __bf16 lA[2][FBM * FBK];
    __shared__ __bf16 lB[2][FBM * FBK];
    const int NTN = N / FBM;
    const int nwg = gridDim.x;
    int bid = blockIdx.x;
    if ((nwg & 7) == 0) bid = (bid & 7) * (nwg >> 3) + (bid >> 3);
    const int tm = bid / NTN, tn = bid % NTN;
    const int tid = threadIdx.x, lane = tid & 63, wid = tid >> 6;
    const int wr = wid >> 1, wc = wid & 1;
    const int srow0 = tid >> 3, skq = tid & 7;
    const float* aptr = A + (size_t)(tm * FBM + srow0) * K + skq * 4;
    const int*   wptr = W + (size_t)(tn * FBM + srow0) * K + skq * 4;
    const size_t rstride = (size_t)32 * K;
    f32x4 sa[4]; i32x4 sw[4];
    auto LOAD = [&](int t) {
#pragma unroll
        for (int j = 0; j < 4; ++j) {
            sa[j] = *(const f32x4*)(aptr + (size_t)t * FBK + j * rstride);
            sw[j] = *(const i32x4*)(wptr + (size_t)t * FBK + j * rstride);
        }
    };
    auto STORE = [&](int buf) {
#pragma unroll
        for (int j = 0; j < 4; ++j) {
            const int idx = swz_elem(srow0 + j * 32, skq * 4);
            bf16x4 va = { (__bf16)sa[j][0], (__bf16)sa[j][1],
                          (__bf16)sa[j][2], (__bf16)sa[j][3] };
            bf16x4 vw = { (__bf16)(float)sw[j][0], (__bf16)(float)sw[j][1],
                          (__bf16)(float)sw[j][2], (__bf16)(float)sw[j][3] };
            *(bf16x4*)&lA[buf][idx] = va;
            *(bf16x4*)&lB[buf][idx] = vw;
        }
    };
    const f32x4 fzero = {0.f, 0.f, 0.f, 0.f};
    f32x4 acc[4][4];
#pragma unroll
    for (int i = 0; i < 4; ++i)
#pragma unroll
        for (int j = 0; j < 4; ++j) acc[i][j] = fzero;
    const int fr = lane & 15, fks = (lane >> 4) * 8;
    LOAD(0); STORE(0); __syncthreads();
    const int NT = K / FBK;
    for (int t = 0; t < NT; ++t) {
        const int buf = t & 1;
        if (t + 1 < NT) LOAD(t + 1);
        bf16x8 af[4], bfg[4];
#pragma unroll
        for (int mi = 0; mi < 4; ++mi)
            af[mi] = *(const bf16x8*)&lA[buf][swz_elem(wr * 64 + mi * 16 + fr, fks)];
#pragma unroll
        for (int ni = 0; ni < 4; ++ni)
            bfg[ni] = *(const bf16x8*)&lB[buf][swz_elem(wc * 64 + ni * 16 + fr, fks)];
#pragma unroll
        for (int mi = 0; mi < 4; ++mi)
#pragma unroll
            for (int ni = 0; ni < 4; ++ni)
                acc[mi][ni] = __builtin_amdgcn_mfma_f32_16x16x32_bf16(
                    af[mi], bfg[ni], acc[mi][ni], 0, 0, 0);
        if (t + 1 < NT) STORE(buf ^ 1);
        __syncthreads();
    }
    const int row0 = tm * FBM + wr * 64 + (lane >> 4) * 4;
    const int col0 = tn * FBM + wc * 64 + fr;
#pragma unroll
    for (int ni = 0; ni < 4; ++ni) {
        const int n = col0 + ni * 16;
        const float sc = scale[n], bs = bias[n];
#pragma unroll
        for (int mi = 0; mi < 4; ++mi) {
            const int m = row0 + mi * 16;
#pragma unroll
            for (int r = 0; r < 4; ++r)
                C[(size_t)(m + r) * N + n] = fmaf(acc[mi][ni][r], sc, bs);
        }
    }
}

extern "C" void kernel_launch(void* const* d_in, const int* in_sizes, int n_in,
                              void* d_out, int out_size, void* d_ws, size_t ws_size,
                              hipStream_t stream) {
    const float* x     = (const float*)d_in[0];
    const int*   w8    = (const int*)d_in[1];
    const float* scale = (const float*)d_in[2];
    const float* bias  = (const float*)d_in[3];
    float*       out   = (float*)d_out;

    const int DOUT = in_sizes[2];
    const int DIN  = in_sizes[1] / DOUT;
    const int M    = in_sizes[0] / DIN;

    const size_t need = ((size_t)M * DIN + (size_t)DOUT * DIN) * sizeof(__bf16);
    const int nwg = (M / BM) * (DOUT / BN);
    const bool ok8 = (ws_size >= need) && (M % BM == 0) && (DOUT % BN == 0) &&
                     (DIN % BK == 0) && (nwg % 8 == 0) && (DIN / BK >= 4);
    if (ok8) {
        __bf16* xb = (__bf16*)d_ws;
        __bf16* wb = xb + (size_t)M * DIN;
        cvt_f32_bf16<<<2048, 256, 0, stream>>>(x, xb, M * DIN / 8);
        cvt_i32_bf16<<<2048, 256, 0, stream>>>(w8, wb, DOUT * DIN / 8);
        hipFuncSetAttribute(reinterpret_cast<const void*>(qlin_gemm_8ph),
                            hipFuncAttributeMaxDynamicSharedMemorySize, 131072);
        qlin_gemm_8ph<<<nwg, 512, 131072, stream>>>(xb, wb, scale, bias, out,
                                                    M, DOUT, DIN);
    } else {
        dim3 grid((M / FBM) * (DOUT / FBM));
        qlin_gemm_reg<<<grid, 256, 0, stream>>>(x, w8, scale, bias, out, M, DOUT, DIN);
    }
}

// Round 5
// 212.494 us; speedup vs baseline: 2.8163x; 1.3875x over previous
//
#include <hip/hip_runtime.h>
#include <hip/hip_bf16.h>

// ---- int8 path: per-row dynamic quant of x, exact int8 W, i32 MFMA accum ----
#define BM 256
#define BN 256
#define BK 64          // 64 int8 = 64 B per LDS row (same geometry as bf16 BK=32)
#define NSLOT 4        // ring of 4 K-tile slots, staged 3 ahead

typedef float  f32x4  __attribute__((ext_vector_type(4)));
typedef int    i32x4  __attribute__((ext_vector_type(4)));
typedef int    i32x16 __attribute__((ext_vector_type(16)));
typedef __bf16 bf16x8 __attribute__((ext_vector_type(8)));
typedef __bf16 bf16x4 __attribute__((ext_vector_type(4)));

__device__ __forceinline__ void gload_lds16(const void* g, void* l) {
    __builtin_amdgcn_global_load_lds(
        (const __attribute__((address_space(1))) void*)g,
        (__attribute__((address_space(3))) void*)l, 16, 0, 0);
}

// ------------- prepass 1: per-row absmax quant of x -> int8 + scale ----------
__global__ __launch_bounds__(256)
void rowquant_x(const float* __restrict__ x, signed char* __restrict__ xq,
                float* __restrict__ xs, int K) {
    const int row = blockIdx.x;
    const float* xr = x + (size_t)row * K;
    const int tid = threadIdx.x;
    const int n4 = K / 4;

    float mx = 0.f;
    for (int i = tid; i < n4; i += 256) {
        f32x4 v = ((const f32x4*)xr)[i];
        mx = fmaxf(mx, fmaxf(fmaxf(fabsf(v[0]), fabsf(v[1])),
                             fmaxf(fabsf(v[2]), fabsf(v[3]))));
    }
#pragma unroll
    for (int off = 32; off; off >>= 1)
        mx = fmaxf(mx, __shfl_xor(mx, off));
    __shared__ float smx[4];
    if ((tid & 63) == 0) smx[tid >> 6] = mx;
    __syncthreads();
    mx = fmaxf(fmaxf(smx[0], smx[1]), fmaxf(smx[2], smx[3]));

    const float inv = mx > 0.f ? 127.f / mx : 0.f;
    if (tid == 0) xs[row] = mx / 127.f;

    unsigned* out = (unsigned*)(xq + (size_t)row * K);
    for (int i = tid; i < n4; i += 256) {     // re-read: row is L1-resident
        f32x4 v = ((const f32x4*)xr)[i];
        int q0 = __float2int_rn(v[0] * inv);
        int q1 = __float2int_rn(v[1] * inv);
        int q2 = __float2int_rn(v[2] * inv);
        int q3 = __float2int_rn(v[3] * inv);
        out[i] = (unsigned)(q0 & 255) | ((unsigned)(q1 & 255) << 8) |
                 ((unsigned)(q2 & 255) << 16) | ((unsigned)(q3 & 255) << 24);
    }
}

// ------------- prepass 2: pack W int32 -> int8 (exact) -----------------------
__global__ __launch_bounds__(256)
void cvt_w_i8(const int* __restrict__ w, unsigned* __restrict__ wq, int n4) {
    int i = blockIdx.x * 256 + threadIdx.x;
    const int stride = gridDim.x * 256;
    for (; i < n4; i += stride) {
        i32x4 v = ((const i32x4*)w)[i];
        wq[i] = (unsigned)(v[0] & 255) | ((unsigned)(v[1] & 255) << 8) |
                ((unsigned)(v[2] & 255) << 16) | ((unsigned)(v[3] & 255) << 24);
    }
}

// ------------- main GEMM: i8 32x32x32 MFMA, free-run counted-vmcnt ring ------
// LDS slot: [256 rows][64 B] per operand, 4 slots each = 128 KiB total.
// XOR swizzle: 16B quad q of row R holds global quad q ^ ((R>>1)&3).
// gload_lds dest is linear (wave base + lane*16) -> inverse swizzle applied to
// the GLOBAL source address; ds_read applies the same XOR (both-sides rule).
// Sync: ONE s_barrier per K-tile, counted vmcnt ladder 8/4/0 (4 loads/tile,
// distance-3 prefetch). WAR-safe: slot re-staged at t+3 was last read at t-1,
// and every wave passed tile t's barrier only after those reads completed.

__global__ __launch_bounds__(512, 2)
void qlin_gemm_i8(const signed char* __restrict__ A,  // [M,K] int8 x-quant
                  const signed char* __restrict__ B,  // [N,K] int8 w
                  const float* __restrict__ xs,       // [M] x row scales
                  const float* __restrict__ scale,    // [N]
                  const float* __restrict__ bias,     // [N]
                  float* __restrict__ C, int M, int N, int K) {
    extern __shared__ signed char lds[];
    signed char* lA = lds;                       // [NSLOT][BM*BK]
    signed char* lB = lds + NSLOT * (BM * BK);

    const int NTN = N / BN;
    const int nwg = gridDim.x;
    int bid = blockIdx.x;
    bid = (bid & 7) * (nwg >> 3) + (bid >> 3);   // XCD swizzle (nwg%8==0)
    const int tm = bid / NTN;
    const int tn = bid % NTN;

    const int tid  = threadIdx.x;
    const int lane = tid & 63;
    const int wid  = tid >> 6;     // 0..7
    const int wr   = wid >> 2;     // 0..1  (M half: 128 rows)
    const int wc   = wid & 3;      // 0..3  (N quarter: 64 cols)

    const int srow = tid >> 2;     // 0..127
    const int scq  = tid & 3;      // 16B quad within 64B row
    const signed char* Abase = A + (size_t)(tm * BM) * K;
    const signed char* Bbase = B + (size_t)(tn * BN) * K;

    const int NT = K / BK;

    auto STAGE_A = [&](int t) {
        const int s = t & (NSLOT - 1);
#pragma unroll
        for (int j = 0; j < 2; ++j) {
            const int R  = j * 128 + srow;
            const int gq = scq ^ ((R >> 1) & 3);
            gload_lds16(Abase + (size_t)R * K + t * BK + gq * 16,
                        lA + s * (BM * BK) + (j * 128 + wid * 16) * BK);
        }
    };
    auto STAGE_B = [&](int t) {
        const int s = t & (NSLOT - 1);
#pragma unroll
        for (int j = 0; j < 2; ++j) {
            const int R  = j * 128 + srow;
            const int gq = scq ^ ((R >> 1) & 3);
            gload_lds16(Bbase + (size_t)R * K + t * BK + gq * 16,
                        lB + s * (BM * BK) + (j * 128 + wid * 16) * BK);
        }
    };

    i32x16 acc[4][2];
#pragma unroll
    for (int mi = 0; mi < 4; ++mi)
#pragma unroll
        for (int ni = 0; ni < 2; ++ni)
#pragma unroll
            for (int r = 0; r < 16; ++r) acc[mi][ni][r] = 0;

    // prologue: stage tiles 0..2 (12 loads/thread)
    for (int u = 0; u < 3 && u < NT; ++u) { STAGE_A(u); STAGE_B(u); }

    const int fr = lane & 31;      // row within 32x32 fragment
    const int fh = lane >> 5;      // k-half selector

    for (int t = 0; t < NT; ++t) {
        const signed char* lAs = lA + (t & (NSLOT - 1)) * (BM * BK);
        const signed char* lBs = lB + (t & (NSLOT - 1)) * (BM * BK);

        const int rem = NT - 1 - t;
        if (rem >= 2)      asm volatile("s_waitcnt vmcnt(8)" ::: "memory");
        else if (rem == 1) asm volatile("s_waitcnt vmcnt(4)" ::: "memory");
        else               asm volatile("s_waitcnt vmcnt(0)" ::: "memory");
        __builtin_amdgcn_s_barrier();   // only barrier this K-tile

        // ---- phase 0: k-step 0 (bytes 0..31 of the 64B row) ----
        if (t + 3 < NT) STAGE_A(t + 3);
        i32x4 af[4], bf[2];
        {
            const int q = fh;          // ks=0
#pragma unroll
            for (int mi = 0; mi < 4; ++mi) {
                const int R = wr * 128 + mi * 32 + fr;
                af[mi] = *(const i32x4*)(lAs + R * BK + ((q ^ ((R >> 1) & 3)) << 4));
            }
#pragma unroll
            for (int ni = 0; ni < 2; ++ni) {
                const int R = wc * 64 + ni * 32 + fr;
                bf[ni] = *(const i32x4*)(lBs + R * BK + ((q ^ ((R >> 1) & 3)) << 4));
            }
        }
        __builtin_amdgcn_s_setprio(1);
#pragma unroll
        for (int mi = 0; mi < 4; ++mi)
#pragma unroll
            for (int ni = 0; ni < 2; ++ni)
                acc[mi][ni] = __builtin_amdgcn_mfma_i32_32x32x32_i8(
                    af[mi], bf[ni], acc[mi][ni], 0, 0, 0);
        __builtin_amdgcn_s_setprio(0);

        // ---- phase 1: k-step 1 (bytes 32..63) ----
        if (t + 3 < NT) STAGE_B(t + 3);
        {
            const int q = 2 + fh;      // ks=1
#pragma unroll
            for (int mi = 0; mi < 4; ++mi) {
                const int R = wr * 128 + mi * 32 + fr;
                af[mi] = *(const i32x4*)(lAs + R * BK + ((q ^ ((R >> 1) & 3)) << 4));
            }
#pragma unroll
            for (int ni = 0; ni < 2; ++ni) {
                const int R = wc * 64 + ni * 32 + fr;
                bf[ni] = *(const i32x4*)(lBs + R * BK + ((q ^ ((R >> 1) & 3)) << 4));
            }
        }
        __builtin_amdgcn_s_setprio(1);
#pragma unroll
        for (int mi = 0; mi < 4; ++mi)
#pragma unroll
            for (int ni = 0; ni < 2; ++ni)
                acc[mi][ni] = __builtin_amdgcn_mfma_i32_32x32x32_i8(
                    af[mi], bf[ni], acc[mi][ni], 0, 0, 0);
        __builtin_amdgcn_s_setprio(0);
    }

    // epilogue: 32x32 C/D layout: col = lane&31, row = (r&3)+8*(r>>2)+4*(lane>>5)
    const int rb = tm * BM + wr * 128 + 4 * fh;
    const int cb = tn * BN + wc * 64 + fr;
#pragma unroll
    for (int mi = 0; mi < 4; ++mi) {
        float sm[16];
#pragma unroll
        for (int r = 0; r < 16; ++r)
            sm[r] = xs[rb + mi * 32 + (r & 3) + 8 * (r >> 2)];
#pragma unroll
        for (int ni = 0; ni < 2; ++ni) {
            const int n = cb + ni * 32;
            const float sc = scale[n];
            const float bs = bias[n];
#pragma unroll
            for (int r = 0; r < 16; ++r) {
                const int m = rb + mi * 32 + (r & 3) + 8 * (r >> 2);
                C[(size_t)m * N + n] = fmaf((float)acc[mi][ni][r], sm[r] * sc, bs);
            }
        }
    }
}

// ---------------- fallback (reg-staged 128^2 bf16, any shape) ----------------
#define FBM 128
#define FBK 32

__device__ __forceinline__ int swz_elem(int row, int e) {
    return row * FBK + (e ^ (((row >> 1) & 3) << 3));
}

__global__ __launch_bounds__(256, 2)
void qlin_gemm_reg(const float* __restrict__ A, const int* __restrict__ W,
                   const float* __restrict__ scale, const float* __restrict__ bias,
                   float* __restrict__ C, int M, int N, int K) {
    __shared__ __bf16 lA[2][FBM * FBK];
    __shared__ __bf16 lB[2][FBM * FBK];
    const int NTN = N / FBM;
    const int nwg = gridDim.x;
    int bid = blockIdx.x;
    if ((nwg & 7) == 0) bid = (bid & 7) * (nwg >> 3) + (bid >> 3);
    const int tm = bid / NTN, tn = bid % NTN;
    const int tid = threadIdx.x, lane = tid & 63, wid = tid >> 6;
    const int wr = wid >> 1, wc = wid & 1;
    const int srow0 = tid >> 3, skq = tid & 7;
    const float* aptr = A + (size_t)(tm * FBM + srow0) * K + skq * 4;
    const int*   wptr = W + (size_t)(tn * FBM + srow0) * K + skq * 4;
    const size_t rstride = (size_t)32 * K;
    f32x4 sa[4]; i32x4 sw[4];
    auto LOAD = [&](int t) {
#pragma unroll
        for (int j = 0; j < 4; ++j) {
            sa[j] = *(const f32x4*)(aptr + (size_t)t * FBK + j * rstride);
            sw[j] = *(const i32x4*)(wptr + (size_t)t * FBK + j * rstride);
        }
    };
    auto STORE = [&](int buf) {
#pragma unroll
        for (int j = 0; j < 4; ++j) {
            const int idx = swz_elem(srow0 + j * 32, skq * 4);
            bf16x4 va = { (__bf16)sa[j][0], (__bf16)sa[j][1],
                          (__bf16)sa[j][2], (__bf16)sa[j][3] };
            bf16x4 vw = { (__bf16)(float)sw[j][0], (__bf16)(float)sw[j][1],
                          (__bf16)(float)sw[j][2], (__bf16)(float)sw[j][3] };
            *(bf16x4*)&lA[buf][idx] = va;
            *(bf16x4*)&lB[buf][idx] = vw;
        }
    };
    const f32x4 fzero = {0.f, 0.f, 0.f, 0.f};
    f32x4 acc[4][4];
#pragma unroll
    for (int i = 0; i < 4; ++i)
#pragma unroll
        for (int j = 0; j < 4; ++j) acc[i][j] = fzero;
    const int fr = lane & 15, fks = (lane >> 4) * 8;
    LOAD(0); STORE(0); __syncthreads();
    const int NT = K / FBK;
    for (int t = 0; t < NT; ++t) {
        const int buf = t & 1;
        if (t + 1 < NT) LOAD(t + 1);
        bf16x8 af[4], bfg[4];
#pragma unroll
        for (int mi = 0; mi < 4; ++mi)
            af[mi] = *(const bf16x8*)&lA[buf][swz_elem(wr * 64 + mi * 16 + fr, fks)];
#pragma unroll
        for (int ni = 0; ni < 4; ++ni)
            bfg[ni] = *(const bf16x8*)&lB[buf][swz_elem(wc * 64 + ni * 16 + fr, fks)];
#pragma unroll
        for (int mi = 0; mi < 4; ++mi)
#pragma unroll
            for (int ni = 0; ni < 4; ++ni)
                acc[mi][ni] = __builtin_amdgcn_mfma_f32_16x16x32_bf16(
                    af[mi], bfg[ni], acc[mi][ni], 0, 0, 0);
        if (t + 1 < NT) STORE(buf ^ 1);
        __syncthreads();
    }
    const int row0 = tm * FBM + wr * 64 + (lane >> 4) * 4;
    const int col0 = tn * FBM + wc * 64 + fr;
#pragma unroll
    for (int ni = 0; ni < 4; ++ni) {
        const int n = col0 + ni * 16;
        const float sc = scale[n], bs = bias[n];
#pragma unroll
        for (int mi = 0; mi < 4; ++mi) {
            const int m = row0 + mi * 16;
#pragma unroll
            for (int r = 0; r < 4; ++r)
                C[(size_t)(m + r) * N + n] = fmaf(acc[mi][ni][r], sc, bs);
        }
    }
}

extern "C" void kernel_launch(void* const* d_in, const int* in_sizes, int n_in,
                              void* d_out, int out_size, void* d_ws, size_t ws_size,
                              hipStream_t stream) {
    const float* x     = (const float*)d_in[0];
    const int*   w8    = (const int*)d_in[1];
    const float* scale = (const float*)d_in[2];
    const float* bias  = (const float*)d_in[3];
    float*       out   = (float*)d_out;

    const int DOUT = in_sizes[2];
    const int DIN  = in_sizes[1] / DOUT;
    const int M    = in_sizes[0] / DIN;

    const size_t need = (size_t)M * DIN + (size_t)DOUT * DIN + (size_t)M * 4;
    const int nwg = (M / BM) * (DOUT / BN);
    const bool ok = (ws_size >= need) && (M % BM == 0) && (DOUT % BN == 0) &&
                    (DIN % BK == 0) && (nwg % 8 == 0) && (DIN / BK >= 4);
    if (ok) {
        signed char* xq = (signed char*)d_ws;
        signed char* wq = xq + (size_t)M * DIN;
        float*       xs = (float*)(wq + (size_t)DOUT * DIN);
        rowquant_x<<<M, 256, 0, stream>>>(x, xq, xs, DIN);
        cvt_w_i8<<<2048, 256, 0, stream>>>(w8, (unsigned*)wq, DOUT * DIN / 4);
        hipFuncSetAttribute(reinterpret_cast<const void*>(qlin_gemm_i8),
                            hipFuncAttributeMaxDynamicSharedMemorySize, 131072);
        qlin_gemm_i8<<<nwg, 512, 131072, stream>>>(xq, wq, xs, scale, bias, out,
                                                   M, DOUT, DIN);
    } else {
        dim3 grid((M / FBM) * (DOUT / FBM));
        qlin_gemm_reg<<<grid, 256, 0, stream>>>(x, w8, scale, bias, out, M, DOUT, DIN);
    }
}

// Round 6
// 208.868 us; speedup vs baseline: 2.8652x; 1.0174x over previous
//
#include <hip/hip_runtime.h>
#include <hip/hip_bf16.h>

// ---- int8 path: per-row dynamic quant of x, exact int8 W, i32 MFMA accum ----
#define BM 256
#define BN 256
#define BK 64          // 64 int8 per row per K-tile
#define NSLOT 4        // ring of 4 K-tile slots, staged 3 ahead

typedef float  f32x4  __attribute__((ext_vector_type(4)));
typedef int    i32x4  __attribute__((ext_vector_type(4)));
typedef int    i32x16 __attribute__((ext_vector_type(16)));
typedef __bf16 bf16x8 __attribute__((ext_vector_type(8)));
typedef __bf16 bf16x4 __attribute__((ext_vector_type(4)));

__device__ __forceinline__ void gload_lds16(const void* g, void* l) {
    __builtin_amdgcn_global_load_lds(
        (const __attribute__((address_space(1))) void*)g,
        (__attribute__((address_space(3))) void*)l, 16, 0, 0);
}

// ------------- prepass 1: per-row absmax quant of x -> int8 + scale ----------
__global__ __launch_bounds__(256)
void rowquant_x(const float* __restrict__ x, signed char* __restrict__ xq,
                float* __restrict__ xs, int K) {
    const int row = blockIdx.x;
    const float* xr = x + (size_t)row * K;
    const int tid = threadIdx.x;
    const int n4 = K / 4;

    float mx = 0.f;
    for (int i = tid; i < n4; i += 256) {
        f32x4 v = ((const f32x4*)xr)[i];
        mx = fmaxf(mx, fmaxf(fmaxf(fabsf(v[0]), fabsf(v[1])),
                             fmaxf(fabsf(v[2]), fabsf(v[3]))));
    }
#pragma unroll
    for (int off = 32; off; off >>= 1)
        mx = fmaxf(mx, __shfl_xor(mx, off));
    __shared__ float smx[4];
    if ((tid & 63) == 0) smx[tid >> 6] = mx;
    __syncthreads();
    mx = fmaxf(fmaxf(smx[0], smx[1]), fmaxf(smx[2], smx[3]));

    const float inv = mx > 0.f ? 127.f / mx : 0.f;
    if (tid == 0) xs[row] = mx / 127.f;

    unsigned* out = (unsigned*)(xq + (size_t)row * K);
    for (int i = tid; i < n4; i += 256) {     // re-read: row is cache-resident
        f32x4 v = ((const f32x4*)xr)[i];
        int q0 = __float2int_rn(v[0] * inv);
        int q1 = __float2int_rn(v[1] * inv);
        int q2 = __float2int_rn(v[2] * inv);
        int q3 = __float2int_rn(v[3] * inv);
        out[i] = (unsigned)(q0 & 255) | ((unsigned)(q1 & 255) << 8) |
                 ((unsigned)(q2 & 255) << 16) | ((unsigned)(q3 & 255) << 24);
    }
}

// ------------- prepass 2: pack W int32 -> int8 (exact) -----------------------
__global__ __launch_bounds__(256)
void cvt_w_i8(const int* __restrict__ w, unsigned* __restrict__ wq, int n4) {
    int i = blockIdx.x * 256 + threadIdx.x;
    const int stride = gridDim.x * 256;
    for (; i < n4; i += stride) {
        i32x4 v = ((const i32x4*)w)[i];
        wq[i] = (unsigned)(v[0] & 255) | ((unsigned)(v[1] & 255) << 8) |
                ((unsigned)(v[2] & 255) << 16) | ((unsigned)(v[3] & 255) << 24);
    }
}

// ------------- main GEMM: i8 32x32x32 MFMA, free-run counted-vmcnt ring ------
// LDS K-tile slot layout (per operand): [2 k-steps][256 rows][32 B], 16 KiB.
//   physical offset(kstep, row, half) = kstep*8192 + row*32
//                                     + (half ^ ((row>>3)&1))*16
// Slot swizzle (half ^ row-bit3) makes every 16-lane subgroup of the phase
// ds_read_b128 cover all 32 banks exactly 2-deep (2-way = free, m136).
// gload_lds writes linearly (wave base + lane*16): wave wid covers rows
// [wid*32, wid*32+32) of one k-step; lane = row_lo*2 + half_phys, and the
// GLOBAL source carries the inverse swizzle (both-sides rule).
// Sync: ONE s_barrier per K-tile, counted vmcnt ladder 8/4/0 (4 loads/tile,
// distance-3 prefetch). WAR-safe: slot re-staged at t+3 was last read at t-1.

__global__ __launch_bounds__(512, 2)
void qlin_gemm_i8(const signed char* __restrict__ A,  // [M,K] int8 x-quant
                  const signed char* __restrict__ B,  // [N,K] int8 w
                  const float* __restrict__ xs,       // [M] x row scales
                  const float* __restrict__ scale,    // [N]
                  const float* __restrict__ bias,     // [N]
                  float* __restrict__ C, int M, int N, int K) {
    extern __shared__ signed char lds[];
    signed char* lA = lds;                       // [NSLOT][16384]
    signed char* lB = lds + NSLOT * (BM * BK);

    const int NTN = N / BN;
    const int nwg = gridDim.x;
    int bid = blockIdx.x;
    bid = (bid & 7) * (nwg >> 3) + (bid >> 3);   // XCD swizzle (nwg%8==0)
    const int tm = bid / NTN;
    const int tn = bid % NTN;

    const int tid  = threadIdx.x;
    const int lane = tid & 63;
    const int wid  = tid >> 6;     // 0..7
    const int wr   = wid >> 2;     // 0..1  (M half: 128 rows)
    const int wc   = wid & 3;      // 0..3  (N quarter: 64 cols)

    // staging map: lane covers row wid*32 + (lane>>1), physical half lane&1
    const int srow  = wid * 32 + (lane >> 1);
    const int shalf = (lane & 1) ^ ((srow >> 3) & 1);   // logical half (inv swz)
    const signed char* Abase = A + (size_t)(tm * BM + srow) * K + shalf * 16;
    const signed char* Bbase = B + (size_t)(tn * BN + srow) * K + shalf * 16;

    const int NT = K / BK;

    auto STAGE_A = [&](int t) {
        signed char* d = lA + (t & (NSLOT - 1)) * (BM * BK) + wid * 1024;
#pragma unroll
        for (int j = 0; j < 2; ++j)   // j = k-step
            gload_lds16(Abase + t * BK + j * 32, d + j * 8192);
    };
    auto STAGE_B = [&](int t) {
        signed char* d = lB + (t & (NSLOT - 1)) * (BM * BK) + wid * 1024;
#pragma unroll
        for (int j = 0; j < 2; ++j)
            gload_lds16(Bbase + t * BK + j * 32, d + j * 8192);
    };

    i32x16 acc[4][2];
#pragma unroll
    for (int mi = 0; mi < 4; ++mi)
#pragma unroll
        for (int ni = 0; ni < 2; ++ni)
#pragma unroll
            for (int r = 0; r < 16; ++r) acc[mi][ni][r] = 0;

    // prologue: stage tiles 0..2 (12 loads/thread)
    for (int u = 0; u < 3 && u < NT; ++u) { STAGE_A(u); STAGE_B(u); }

    const int fr = lane & 31;      // M/N row within 32x32 fragment
    const int fh = lane >> 5;      // k-half selector (16 B)
    const int swz = (fr >> 3) & 1; // row-bit3 slot swizzle

    for (int t = 0; t < NT; ++t) {
        const signed char* lAs = lA + (t & (NSLOT - 1)) * (BM * BK);
        const signed char* lBs = lB + (t & (NSLOT - 1)) * (BM * BK);

        const int rem = NT - 1 - t;
        if (rem >= 2)      asm volatile("s_waitcnt vmcnt(8)" ::: "memory");
        else if (rem == 1) asm volatile("s_waitcnt vmcnt(4)" ::: "memory");
        else               asm volatile("s_waitcnt vmcnt(0)" ::: "memory");
        __builtin_amdgcn_s_barrier();   // only barrier this K-tile

        // ---- phase 0: k-step 0 ----
        if (t + 3 < NT) STAGE_A(t + 3);
        i32x4 af[4], bf[2];
        {
            const int ho = ((fh ^ swz) << 4);
#pragma unroll
            for (int mi = 0; mi < 4; ++mi) {
                const int R = wr * 128 + mi * 32 + fr;
                af[mi] = *(const i32x4*)(lAs + R * 32 + ho);
            }
#pragma unroll
            for (int ni = 0; ni < 2; ++ni) {
                const int R = wc * 64 + ni * 32 + fr;
                bf[ni] = *(const i32x4*)(lBs + R * 32 + ho);
            }
        }
        __builtin_amdgcn_s_setprio(1);
#pragma unroll
        for (int mi = 0; mi < 4; ++mi)
#pragma unroll
            for (int ni = 0; ni < 2; ++ni)
                acc[mi][ni] = __builtin_amdgcn_mfma_i32_32x32x32_i8(
                    af[mi], bf[ni], acc[mi][ni], 0, 0, 0);
        __builtin_amdgcn_s_setprio(0);

        // ---- phase 1: k-step 1 (+8192) ----
        if (t + 3 < NT) STAGE_B(t + 3);
        {
            const int ho = 8192 + ((fh ^ swz) << 4);
#pragma unroll
            for (int mi = 0; mi < 4; ++mi) {
                const int R = wr * 128 + mi * 32 + fr;
                af[mi] = *(const i32x4*)(lAs + R * 32 + ho);
            }
#pragma unroll
            for (int ni = 0; ni < 2; ++ni) {
                const int R = wc * 64 + ni * 32 + fr;
                bf[ni] = *(const i32x4*)(lBs + R * 32 + ho);
            }
        }
        __builtin_amdgcn_s_setprio(1);
#pragma unroll
        for (int mi = 0; mi < 4; ++mi)
#pragma unroll
            for (int ni = 0; ni < 2; ++ni)
                acc[mi][ni] = __builtin_amdgcn_mfma_i32_32x32x32_i8(
                    af[mi], bf[ni], acc[mi][ni], 0, 0, 0);
        __builtin_amdgcn_s_setprio(0);
    }

    // epilogue: 32x32 C/D layout: col = lane&31, row = (r&3)+8*(r>>2)+4*(lane>>5)
    const int rb = tm * BM + wr * 128 + 4 * fh;
    const int cb = tn * BN + wc * 64 + fr;
#pragma unroll
    for (int mi = 0; mi < 4; ++mi) {
        float sm[16];
#pragma unroll
        for (int r = 0; r < 16; ++r)
            sm[r] = xs[rb + mi * 32 + (r & 3) + 8 * (r >> 2)];
#pragma unroll
        for (int ni = 0; ni < 2; ++ni) {
            const int n = cb + ni * 32;
            const float sc = scale[n];
            const float bs = bias[n];
#pragma unroll
            for (int r = 0; r < 16; ++r) {
                const int m = rb + mi * 32 + (r & 3) + 8 * (r >> 2);
                C[(size_t)m * N + n] = fmaf((float)acc[mi][ni][r], sm[r] * sc, bs);
            }
        }
    }
}

// ---------------- fallback (reg-staged 128^2 bf16, any shape) ----------------
#define FBM 128
#define FBK 32

__device__ __forceinline__ int swz_elem(int row, int e) {
    return row * FBK + (e ^ (((row >> 1) & 3) << 3));
}

__global__ __launch_bounds__(256, 2)
void qlin_gemm_reg(const float* __restrict__ A, const int* __restrict__ W,
                   const float* __restrict__ scale, const float* __restrict__ bias,
                   float* __restrict__ C, int M, int N, int K) {
    __shared__ __bf16 lA[2][FBM * FBK];
    __shared__ __bf16 lB[2][FBM * FBK];
    const int NTN = N / FBM;
    const int nwg = gridDim.x;
    int bid = blockIdx.x;
    if ((nwg & 7) == 0) bid = (bid & 7) * (nwg >> 3) + (bid >> 3);
    const int tm = bid / NTN, tn = bid % NTN;
    const int tid = threadIdx.x, lane = tid & 63, wid = tid >> 6;
    const int wr = wid >> 1, wc = wid & 1;
    const int srow0 = tid >> 3, skq = tid & 7;
    const float* aptr = A + (size_t)(tm * FBM + srow0) * K + skq * 4;
    const int*   wptr = W + (size_t)(tn * FBM + srow0) * K + skq * 4;
    const size_t rstride = (size_t)32 * K;
    f32x4 sa[4]; i32x4 sw[4];
    auto LOAD = [&](int t) {
#pragma unroll
        for (int j = 0; j < 4; ++j) {
            sa[j] = *(const f32x4*)(aptr + (size_t)t * FBK + j * rstride);
            sw[j] = *(const i32x4*)(wptr + (size_t)t * FBK + j * rstride);
        }
    };
    auto STORE = [&](int buf) {
#pragma unroll
        for (int j = 0; j < 4; ++j) {
            const int idx = swz_elem(srow0 + j * 32, skq * 4);
            bf16x4 va = { (__bf16)sa[j][0], (__bf16)sa[j][1],
                          (__bf16)sa[j][2], (__bf16)sa[j][3] };
            bf16x4 vw = { (__bf16)(float)sw[j][0], (__bf16)(float)sw[j][1],
                          (__bf16)(float)sw[j][2], (__bf16)(float)sw[j][3] };
            *(bf16x4*)&lA[buf][idx] = va;
            *(bf16x4*)&lB[buf][idx] = vw;
        }
    };
    const f32x4 fzero = {0.f, 0.f, 0.f, 0.f};
    f32x4 acc[4][4];
#pragma unroll
    for (int i = 0; i < 4; ++i)
#pragma unroll
        for (int j = 0; j < 4; ++j) acc[i][j] = fzero;
    const int fr = lane & 15, fks = (lane >> 4) * 8;
    LOAD(0); STORE(0); __syncthreads();
    const int NT = K / FBK;
    for (int t = 0; t < NT; ++t) {
        const int buf = t & 1;
        if (t + 1 < NT) LOAD(t + 1);
        bf16x8 af[4], bfg[4];
#pragma unroll
        for (int mi = 0; mi < 4; ++mi)
            af[mi] = *(const bf16x8*)&lA[buf][swz_elem(wr * 64 + mi * 16 + fr, fks)];
#pragma unroll
        for (int ni = 0; ni < 4; ++ni)
            bfg[ni] = *(const bf16x8*)&lB[buf][swz_elem(wc * 64 + ni * 16 + fr, fks)];
#pragma unroll
        for (int mi = 0; mi < 4; ++mi)
#pragma unroll
            for (int ni = 0; ni < 4; ++ni)
                acc[mi][ni] = __builtin_amdgcn_mfma_f32_16x16x32_bf16(
                    af[mi], bfg[ni], acc[mi][ni], 0, 0, 0);
        if (t + 1 < NT) STORE(buf ^ 1);
        __syncthreads();
    }
    const int row0 = tm * FBM + wr * 64 + (lane >> 4) * 4;
    const int col0 = tn * FBM + wc * 64 + fr;
#pragma unroll
    for (int ni = 0; ni < 4; ++ni) {
        const int n = col0 + ni * 16;
        const float sc = scale[n], bs = bias[n];
#pragma unroll
        for (int mi = 0; mi < 4; ++mi) {
            const int m = row0 + mi * 16;
#pragma unroll
            for (int r = 0; r < 4; ++r)
                C[(size_t)(m + r) * N + n] = fmaf(acc[mi][ni][r], sc, bs);
        }
    }
}

extern "C" void kernel_launch(void* const* d_in, const int* in_sizes, int n_in,
                              void* d_out, int out_size, void* d_ws, size_t ws_size,
                              hipStream_t stream) {
    const float* x     = (const float*)d_in[0];
    const int*   w8    = (const int*)d_in[1];
    const float* scale = (const float*)d_in[2];
    const float* bias  = (const float*)d_in[3];
    float*       out   = (float*)d_out;

    const int DOUT = in_sizes[2];
    const int DIN  = in_sizes[1] / DOUT;
    const int M    = in_sizes[0] / DIN;

    const size_t need = (size_t)M * DIN + (size_t)DOUT * DIN + (size_t)M * 4;
    const int nwg = (M / BM) * (DOUT / BN);
    const bool ok = (ws_size >= need) && (M % BM == 0) && (DOUT % BN == 0) &&
                    (DIN % BK == 0) && (nwg % 8 == 0) && (DIN / BK >= 4);
    if (ok) {
        signed char* xq = (signed char*)d_ws;
        signed char* wq = xq + (size_t)M * DIN;
        float*       xs = (float*)(wq + (size_t)DOUT * DIN);
        rowquant_x<<<M, 256, 0, stream>>>(x, xq, xs, DIN);
        cvt_w_i8<<<2048, 256, 0, stream>>>(w8, (unsigned*)wq, DOUT * DIN / 4);
        hipFuncSetAttribute(reinterpret_cast<const void*>(qlin_gemm_i8),
                            hipFuncAttributeMaxDynamicSharedMemorySize, 131072);
        qlin_gemm_i8<<<nwg, 512, 131072, stream>>>(xq, wq, xs, scale, bias, out,
                                                   M, DOUT, DIN);
    } else {
        dim3 grid((M / FBM) * (DOUT / FBM));
        qlin_gemm_reg<<<grid, 256, 0, stream>>>(x, w8, scale, bias, out, M, DOUT, DIN);
    }
}

// Round 7
// 208.770 us; speedup vs baseline: 2.8666x; 1.0005x over previous
//
#include <hip/hip_runtime.h>
#include <hip/hip_bf16.h>

// ---- int8 path: per-row dynamic quant of x, exact int8 W, i32 MFMA accum ----
#define BM 256
#define BN 256
#define BK 64          // 64 int8 per row per K-tile
#define NSLOT 4        // ring of 4 K-tile slots, staged 3 ahead

typedef float  f32x4  __attribute__((ext_vector_type(4)));
typedef int    i32x4  __attribute__((ext_vector_type(4)));
typedef int    i32x16 __attribute__((ext_vector_type(16)));
typedef __bf16 bf16x8 __attribute__((ext_vector_type(8)));
typedef __bf16 bf16x4 __attribute__((ext_vector_type(4)));

__device__ __forceinline__ void gload_lds16(const void* g, void* l) {
    __builtin_amdgcn_global_load_lds(
        (const __attribute__((address_space(1))) void*)g,
        (__attribute__((address_space(3))) void*)l, 16, 0, 0);
}

// ------------- prepass 1: per-row absmax quant of x -> int8 + scale ----------
__global__ __launch_bounds__(256)
void rowquant_x(const float* __restrict__ x, signed char* __restrict__ xq,
                float* __restrict__ xs, int K) {
    const int row = blockIdx.x;
    const float* xr = x + (size_t)row * K;
    const int tid = threadIdx.x;
    const int n4 = K / 4;

    float mx = 0.f;
    for (int i = tid; i < n4; i += 256) {
        f32x4 v = ((const f32x4*)xr)[i];
        mx = fmaxf(mx, fmaxf(fmaxf(fabsf(v[0]), fabsf(v[1])),
                             fmaxf(fabsf(v[2]), fabsf(v[3]))));
    }
#pragma unroll
    for (int off = 32; off; off >>= 1)
        mx = fmaxf(mx, __shfl_xor(mx, off));
    __shared__ float smx[4];
    if ((tid & 63) == 0) smx[tid >> 6] = mx;
    __syncthreads();
    mx = fmaxf(fmaxf(smx[0], smx[1]), fmaxf(smx[2], smx[3]));

    const float inv = mx > 0.f ? 127.f / mx : 0.f;
    if (tid == 0) xs[row] = mx / 127.f;

    unsigned* out = (unsigned*)(xq + (size_t)row * K);
    for (int i = tid; i < n4; i += 256) {     // re-read: row is cache-resident
        f32x4 v = ((const f32x4*)xr)[i];
        int q0 = __float2int_rn(v[0] * inv);
        int q1 = __float2int_rn(v[1] * inv);
        int q2 = __float2int_rn(v[2] * inv);
        int q3 = __float2int_rn(v[3] * inv);
        out[i] = (unsigned)(q0 & 255) | ((unsigned)(q1 & 255) << 8) |
                 ((unsigned)(q2 & 255) << 16) | ((unsigned)(q3 & 255) << 24);
    }
}

// ------------- prepass 2: pack W int32 -> int8 (exact) -----------------------
__global__ __launch_bounds__(256)
void cvt_w_i8(const int* __restrict__ w, unsigned* __restrict__ wq, int n4) {
    int i = blockIdx.x * 256 + threadIdx.x;
    const int stride = gridDim.x * 256;
    for (; i < n4; i += stride) {
        i32x4 v = ((const i32x4*)w)[i];
        wq[i] = (unsigned)(v[0] & 255) | ((unsigned)(v[1] & 255) << 8) |
                ((unsigned)(v[2] & 255) << 16) | ((unsigned)(v[3] & 255) << 24);
    }
}

// ------------- main GEMM: i8 32x32x32 MFMA, free-run counted-vmcnt ring ------
// LDS K-tile slot (per operand): [2 k-steps][256 rows][32 B], 16 KiB.
//   phys(kstep,row,half) = kstep*8192 + row*32 + (half ^ ((row>>3)&1))*16
// 2-way bank pattern on ds_read_b128 (free, m136); conflicts measured 0.
// gload_lds writes linearly; GLOBAL source carries the inverse swizzle.
// Sync: ONE s_barrier per K-tile, counted vmcnt ladder 8/4/0, distance-3
// prefetch, NSLOT=4 ring. WAR-safe: every ds_read is consumed by an MFMA
// before the wave's next barrier (lgkm drains), so slot reuse is ordered.
// R7 change: ALL 12 ds_reads issued at tile top, both STAGEs next, then a
// single setprio-bracketed 16-MFMA cluster -> read latency exposed once per
// tile and never fenced away from the MFMA shadow by setprio.

__global__ __launch_bounds__(512, 2)
void qlin_gemm_i8(const signed char* __restrict__ A,  // [M,K] int8 x-quant
                  const signed char* __restrict__ B,  // [N,K] int8 w
                  const float* __restrict__ xs,       // [M] x row scales
                  const float* __restrict__ scale,    // [N]
                  const float* __restrict__ bias,     // [N]
                  float* __restrict__ C, int M, int N, int K) {
    extern __shared__ signed char lds[];
    signed char* lA = lds;                       // [NSLOT][16384]
    signed char* lB = lds + NSLOT * (BM * BK);

    const int NTN = N / BN;
    const int nwg = gridDim.x;
    int bid = blockIdx.x;
    bid = (bid & 7) * (nwg >> 3) + (bid >> 3);   // XCD swizzle (nwg%8==0)
    const int tm = bid / NTN;
    const int tn = bid % NTN;

    const int tid  = threadIdx.x;
    const int lane = tid & 63;
    const int wid  = tid >> 6;     // 0..7
    const int wr   = wid >> 2;     // 0..1  (M half: 128 rows)
    const int wc   = wid & 3;      // 0..3  (N quarter: 64 cols)

    // staging map: lane covers row wid*32 + (lane>>1), physical half lane&1
    const int srow  = wid * 32 + (lane >> 1);
    const int shalf = (lane & 1) ^ ((srow >> 3) & 1);   // logical half (inv swz)
    const signed char* Abase = A + (size_t)(tm * BM + srow) * K + shalf * 16;
    const signed char* Bbase = B + (size_t)(tn * BN + srow) * K + shalf * 16;

    const int NT = K / BK;

    auto STAGE_A = [&](int t) {
        signed char* d = lA + (t & (NSLOT - 1)) * (BM * BK) + wid * 1024;
#pragma unroll
        for (int j = 0; j < 2; ++j)   // j = k-step
            gload_lds16(Abase + t * BK + j * 32, d + j * 8192);
    };
    auto STAGE_B = [&](int t) {
        signed char* d = lB + (t & (NSLOT - 1)) * (BM * BK) + wid * 1024;
#pragma unroll
        for (int j = 0; j < 2; ++j)
            gload_lds16(Bbase + t * BK + j * 32, d + j * 8192);
    };

    i32x16 acc[4][2];
#pragma unroll
    for (int mi = 0; mi < 4; ++mi)
#pragma unroll
        for (int ni = 0; ni < 2; ++ni)
#pragma unroll
            for (int r = 0; r < 16; ++r) acc[mi][ni][r] = 0;

    // prologue: stage tiles 0..2 (12 loads/thread)
    for (int u = 0; u < 3 && u < NT; ++u) { STAGE_A(u); STAGE_B(u); }

    const int fr = lane & 31;      // M/N row within 32x32 fragment
    const int fh = lane >> 5;      // k-half selector (16 B)
    const int swz = (fr >> 3) & 1; // row-bit3 slot swizzle

    for (int t = 0; t < NT; ++t) {
        const signed char* lAs = lA + (t & (NSLOT - 1)) * (BM * BK);
        const signed char* lBs = lB + (t & (NSLOT - 1)) * (BM * BK);

        const int rem = NT - 1 - t;
        if (rem >= 2)      asm volatile("s_waitcnt vmcnt(8)" ::: "memory");
        else if (rem == 1) asm volatile("s_waitcnt vmcnt(4)" ::: "memory");
        else               asm volatile("s_waitcnt vmcnt(0)" ::: "memory");
        __builtin_amdgcn_s_barrier();   // only barrier this K-tile

        // ---- all 12 ds_reads upfront (both k-steps) ----
        const int ho0 = ((fh ^ swz) << 4);
        const int ho1 = 8192 + ho0;
        i32x4 af0[4], af1[4], bf0[2], bf1[2];
#pragma unroll
        for (int mi = 0; mi < 4; ++mi) {
            const int R = wr * 128 + mi * 32 + fr;
            af0[mi] = *(const i32x4*)(lAs + R * 32 + ho0);
        }
#pragma unroll
        for (int ni = 0; ni < 2; ++ni) {
            const int R = wc * 64 + ni * 32 + fr;
            bf0[ni] = *(const i32x4*)(lBs + R * 32 + ho0);
        }
#pragma unroll
        for (int mi = 0; mi < 4; ++mi) {
            const int R = wr * 128 + mi * 32 + fr;
            af1[mi] = *(const i32x4*)(lAs + R * 32 + ho1);
        }
#pragma unroll
        for (int ni = 0; ni < 2; ++ni) {
            const int R = wc * 64 + ni * 32 + fr;
            bf1[ni] = *(const i32x4*)(lBs + R * 32 + ho1);
        }

        // stage issue sits in the ds_read latency shadow
        if (t + 3 < NT) { STAGE_A(t + 3); STAGE_B(t + 3); }

        // ---- single 16-MFMA cluster ----
        __builtin_amdgcn_s_setprio(1);
#pragma unroll
        for (int mi = 0; mi < 4; ++mi)
#pragma unroll
            for (int ni = 0; ni < 2; ++ni)
                acc[mi][ni] = __builtin_amdgcn_mfma_i32_32x32x32_i8(
                    af0[mi], bf0[ni], acc[mi][ni], 0, 0, 0);
#pragma unroll
        for (int mi = 0; mi < 4; ++mi)
#pragma unroll
            for (int ni = 0; ni < 2; ++ni)
                acc[mi][ni] = __builtin_amdgcn_mfma_i32_32x32x32_i8(
                    af1[mi], bf1[ni], acc[mi][ni], 0, 0, 0);
        __builtin_amdgcn_s_setprio(0);
    }

    // epilogue: 32x32 C/D layout: col = lane&31, row = (r&3)+8*(r>>2)+4*(lane>>5)
    const int rb = tm * BM + wr * 128 + 4 * fh;
    const int cb = tn * BN + wc * 64 + fr;
#pragma unroll
    for (int mi = 0; mi < 4; ++mi) {
        float sm[16];
#pragma unroll
        for (int r = 0; r < 16; ++r)
            sm[r] = xs[rb + mi * 32 + (r & 3) + 8 * (r >> 2)];
#pragma unroll
        for (int ni = 0; ni < 2; ++ni) {
            const int n = cb + ni * 32;
            const float sc = scale[n];
            const float bs = bias[n];
#pragma unroll
            for (int r = 0; r < 16; ++r) {
                const int m = rb + mi * 32 + (r & 3) + 8 * (r >> 2);
                C[(size_t)m * N + n] = fmaf((float)acc[mi][ni][r], sm[r] * sc, bs);
            }
        }
    }
}

// ---------------- fallback (reg-staged 128^2 bf16, any shape) ----------------
#define FBM 128
#define FBK 32

__device__ __forceinline__ int swz_elem(int row, int e) {
    return row * FBK + (e ^ (((row >> 1) & 3) << 3));
}

__global__ __launch_bounds__(256, 2)
void qlin_gemm_reg(const float* __restrict__ A, const int* __restrict__ W,
                   const float* __restrict__ scale, const float* __restrict__ bias,
                   float* __restrict__ C, int M, int N, int K) {
    __shared__ __bf16 lA[2][FBM * FBK];
    __shared__ __bf16 lB[2][FBM * FBK];
    const int NTN = N / FBM;
    const int nwg = gridDim.x;
    int bid = blockIdx.x;
    if ((nwg & 7) == 0) bid = (bid & 7) * (nwg >> 3) + (bid >> 3);
    const int tm = bid / NTN, tn = bid % NTN;
    const int tid = threadIdx.x, lane = tid & 63, wid = tid >> 6;
    const int wr = wid >> 1, wc = wid & 1;
    const int srow0 = tid >> 3, skq = tid & 7;
    const float* aptr = A + (size_t)(tm * FBM + srow0) * K + skq * 4;
    const int*   wptr = W + (size_t)(tn * FBM + srow0) * K + skq * 4;
    const size_t rstride = (size_t)32 * K;
    f32x4 sa[4]; i32x4 sw[4];
    auto LOAD = [&](int t) {
#pragma unroll
        for (int j = 0; j < 4; ++j) {
            sa[j] = *(const f32x4*)(aptr + (size_t)t * FBK + j * rstride);
            sw[j] = *(const i32x4*)(wptr + (size_t)t * FBK + j * rstride);
        }
    };
    auto STORE = [&](int buf) {
#pragma unroll
        for (int j = 0; j < 4; ++j) {
            const int idx = swz_elem(srow0 + j * 32, skq * 4);
            bf16x4 va = { (__bf16)sa[j][0], (__bf16)sa[j][1],
                          (__bf16)sa[j][2], (__bf16)sa[j][3] };
            bf16x4 vw = { (__bf16)(float)sw[j][0], (__bf16)(float)sw[j][1],
                          (__bf16)(float)sw[j][2], (__bf16)(float)sw[j][3] };
            *(bf16x4*)&lA[buf][idx] = va;
            *(bf16x4*)&lB[buf][idx] = vw;
        }
    };
    const f32x4 fzero = {0.f, 0.f, 0.f, 0.f};
    f32x4 acc[4][4];
#pragma unroll
    for (int i = 0; i < 4; ++i)
#pragma unroll
        for (int j = 0; j < 4; ++j) acc[i][j] = fzero;
    const int fr = lane & 15, fks = (lane >> 4) * 8;
    LOAD(0); STORE(0); __syncthreads();
    const int NT = K / FBK;
    for (int t = 0; t < NT; ++t) {
        const int buf = t & 1;
        if (t + 1 < NT) LOAD(t + 1);
        bf16x8 af[4], bfg[4];
#pragma unroll
        for (int mi = 0; mi < 4; ++mi)
            af[mi] = *(const bf16x8*)&lA[buf][swz_elem(wr * 64 + mi * 16 + fr, fks)];
#pragma unroll
        for (int ni = 0; ni < 4; ++ni)
            bfg[ni] = *(const bf16x8*)&lB[buf][swz_elem(wc * 64 + ni * 16 + fr, fks)];
#pragma unroll
        for (int mi = 0; mi < 4; ++mi)
#pragma unroll
            for (int ni = 0; ni < 4; ++ni)
                acc[mi][ni] = __builtin_amdgcn_mfma_f32_16x16x32_bf16(
                    af[mi], bfg[ni], acc[mi][ni], 0, 0, 0);
        if (t + 1 < NT) STORE(buf ^ 1);
        __syncthreads();
    }
    const int row0 = tm * FBM + wr * 64 + (lane >> 4) * 4;
    const int col0 = tn * FBM + wc * 64 + fr;
#pragma unroll
    for (int ni = 0; ni < 4; ++ni) {
        const int n = col0 + ni * 16;
        const float sc = scale[n], bs = bias[n];
#pragma unroll
        for (int mi = 0; mi < 4; ++mi) {
            const int m = row0 + mi * 16;
#pragma unroll
            for (int r = 0; r < 4; ++r)
                C[(size_t)(m + r) * N + n] = fmaf(acc[mi][ni][r], sc, bs);
        }
    }
}

extern "C" void kernel_launch(void* const* d_in, const int* in_sizes, int n_in,
                              void* d_out, int out_size, void* d_ws, size_t ws_size,
                              hipStream_t stream) {
    const float* x     = (const float*)d_in[0];
    const int*   w8    = (const int*)d_in[1];
    const float* scale = (const float*)d_in[2];
    const float* bias  = (const float*)d_in[3];
    float*       out   = (float*)d_out;

    const int DOUT = in_sizes[2];
    const int DIN  = in_sizes[1] / DOUT;
    const int M    = in_sizes[0] / DIN;

    const size_t need = (size_t)M * DIN + (size_t)DOUT * DIN + (size_t)M * 4;
    const int nwg = (M / BM) * (DOUT / BN);
    const bool ok = (ws_size >= need) && (M % BM == 0) && (DOUT % BN == 0) &&
                    (DIN % BK == 0) && (nwg % 8 == 0) && (DIN / BK >= 4);
    if (ok) {
        signed char* xq = (signed char*)d_ws;
        signed char* wq = xq + (size_t)M * DIN;
        float*       xs = (float*)(wq + (size_t)DOUT * DIN);
        rowquant_x<<<M, 256, 0, stream>>>(x, xq, xs, DIN);
        cvt_w_i8<<<2048, 256, 0, stream>>>(w8, (unsigned*)wq, DOUT * DIN / 4);
        hipFuncSetAttribute(reinterpret_cast<const void*>(qlin_gemm_i8),
                            hipFuncAttributeMaxDynamicSharedMemorySize, 131072);
        qlin_gemm_i8<<<nwg, 512, 131072, stream>>>(xq, wq, xs, scale, bias, out,
                                                   M, DOUT, DIN);
    } else {
        dim3 grid((M / FBM) * (DOUT / FBM));
        qlin_gemm_reg<<<grid, 256, 0, stream>>>(x, w8, scale, bias, out, M, DOUT, DIN);
    }
}